// Round 25
// baseline (103.107 us; speedup 1.0000x reference)
//
#include <hip/hip_runtime.h>
#include <hip/hip_bf16.h>
#include <stdint.h>

// Problem constants
#define BB    32
#define CIN   1024
#define TT    7
#define HHWW  196      // 14*14
#define HW4   49       // 196/4
#define CI    512      // C_INTER
#define TMID  3
#define MM    (BB*HHWW)   // 6272 = 49*128
#define NCH   32          // alpha c-chunks (R25: 16 -> 32 for 2x latency hiding)
#define CSZ   32          // c per chunk

using bf16 = __hip_bfloat16;
typedef __attribute__((ext_vector_type(8))) short short8;
typedef __attribute__((ext_vector_type(4))) short s16x4;
typedef __attribute__((ext_vector_type(4))) float f32x4;

__device__ __forceinline__ void gload_lds16(const void* g, void* l) {
    __builtin_amdgcn_global_load_lds((const __attribute__((address_space(1))) void*)g,
                                     (__attribute__((address_space(3))) void*)l, 16, 0, 0);
}

// ---------------------------------------------------------------- GEMM body (128x128, dbuf, counted vmcnt, T2 swizzle) ----
// TN: A[m][k], Bt[n][k], bf16, f32 accum. 256 threads, 2x2 waves.
// LDS: 16B granule g holds global (r=g>>3, c8=(g&7)^(r&7)) — XOR spread across 8
// bank-quads; linear gload_lds dest + pre-swizzled global src + swizzled read (rule #21).
// Per K-iter: stage(next) -> s_waitcnt vmcnt(8) -> s_barrier -> ds_read+MFMA -> s_barrier.
template <int EPI>
__device__ __forceinline__ void gemm_body(const bf16* __restrict__ A, const bf16* __restrict__ Bt,
                                          void* __restrict__ Cout, const float* __restrict__ bias,
                                          int M, int N, int K, int bm, int bn,
                                          bf16* As, bf16* Bs) {
    int tid = threadIdx.x;
    int wid = tid >> 6, lane = tid & 63;
    int wr = wid >> 1, wc = wid & 1;
    f32x4 acc[4][4] = {};
    const bf16* Ab = A + (size_t)bm * 128 * K;
    const bf16* Bb = Bt + (size_t)bn * 128 * K;
    int row = lane & 15;
    int sw = row & 7;

    auto stage = [&](int buf, int k0) {
        #pragma unroll
        for (int it = 0; it < 4; ++it) {
            int g = it * 256 + tid;
            int r = g >> 3;
            int src8 = (g & 7) ^ (r & 7);
            gload_lds16(Ab + (size_t)r * K + k0 + src8 * 8, &As[buf * 8192 + g * 8]);
            gload_lds16(Bb + (size_t)r * K + k0 + src8 * 8, &Bs[buf * 8192 + g * 8]);
        }
    };

    stage(0, 0);
    int cur = 0;
    for (int k0 = 0; k0 < K; k0 += 64) {
        if (k0 + 64 < K) {
            stage(cur ^ 1, k0 + 64);
            asm volatile("s_waitcnt vmcnt(8)" ::: "memory");
        } else {
            asm volatile("s_waitcnt vmcnt(0)" ::: "memory");
        }
        __builtin_amdgcn_s_barrier();
        bf16* Ac = &As[cur * 8192];
        bf16* Bc = &Bs[cur * 8192];
        #pragma unroll
        for (int kk = 0; kk < 2; ++kk) {
            int kb8 = kk * 4 + (lane >> 4);
            int rd8 = kb8 ^ sw;
            short8 a[4], b[4];
            #pragma unroll
            for (int mi = 0; mi < 4; ++mi) {
                int arow = wr * 64 + mi * 16 + row;
                a[mi] = *(const short8*)&Ac[(arow * 8 + rd8) * 8];
            }
            #pragma unroll
            for (int ni = 0; ni < 4; ++ni) {
                int brow = wc * 64 + ni * 16 + row;
                b[ni] = *(const short8*)&Bc[(brow * 8 + rd8) * 8];
            }
            #pragma unroll
            for (int mi = 0; mi < 4; ++mi)
                #pragma unroll
                for (int ni = 0; ni < 4; ++ni)
                    acc[mi][ni] = __builtin_amdgcn_mfma_f32_16x16x32_bf16(a[mi], b[ni], acc[mi][ni], 0, 0, 0);
        }
        __builtin_amdgcn_s_barrier();
        cur ^= 1;
    }

    int col_l = lane & 15, row_l = (lane >> 4) * 4;
    if constexpr (EPI == 0) {
        bf16* C = (bf16*)Cout;
        #pragma unroll
        for (int mi = 0; mi < 4; ++mi) {
            int row0 = bm * 128 + wr * 64 + mi * 16 + row_l;
            #pragma unroll
            for (int ni = 0; ni < 4; ++ni) {
                int col = bn * 128 + wc * 64 + ni * 16 + col_l;
                #pragma unroll
                for (int r = 0; r < 4; ++r)
                    C[(size_t)(row0 + r) * N + col] = __float2bfloat16(acc[mi][ni][r]);
            }
        }
    } else {
        float* Cf = (float*)Cout;
        #pragma unroll
        for (int ni = 0; ni < 4; ++ni) {
            int n = bn * 128 + wc * 64 + ni * 16 + col_l;
            float bz = bias[n];
            #pragma unroll
            for (int mi = 0; mi < 4; ++mi) {
                int m0 = bm * 128 + wr * 64 + mi * 16 + row_l;
                int b = m0 / HHWW;
                int hw0 = m0 - b * HHWW;
                f32x4 v = acc[mi][ni];
                v[0] += bz; v[1] += bz; v[2] += bz; v[3] += bz;
                *(f32x4*)&Cf[((size_t)b * CIN + n) * HHWW + hw0] = v;
            }
        }
    }
}

// ---------------------------------------------------------------- gemm0 small body (64x64, single-buf, T2 swizzle) ----
__device__ __forceinline__ void gemm0_small(const bf16* __restrict__ A, const bf16* __restrict__ Bt,
                                            bf16* __restrict__ C, int bm, int bn, char* smem) {
    bf16* As = (bf16*)smem;            // 8 KB
    bf16* Bs = (bf16*)(smem + 8192);   // 8 KB
    const int K = 512, N = 1024;
    int tid = threadIdx.x;
    int wid = tid >> 6, lane = tid & 63;
    int wr = wid >> 1, wc = wid & 1;
    f32x4 acc[2][2] = {};
    const bf16* Ab = A + (size_t)bm * 64 * K;
    const bf16* Bb = Bt + (size_t)bn * 64 * K;
    int row = lane & 15;
    int sw = row & 7;

    for (int k0 = 0; k0 < K; k0 += 64) {
        #pragma unroll
        for (int it = 0; it < 2; ++it) {
            int g = it * 256 + tid;
            int r = g >> 3;
            int src8 = (g & 7) ^ (r & 7);
            gload_lds16(Ab + (size_t)r * K + k0 + src8 * 8, &As[g * 8]);
            gload_lds16(Bb + (size_t)r * K + k0 + src8 * 8, &Bs[g * 8]);
        }
        __syncthreads();
        #pragma unroll
        for (int kk = 0; kk < 2; ++kk) {
            int kb8 = kk * 4 + (lane >> 4);
            int rd8 = kb8 ^ sw;
            short8 a[2], b[2];
            #pragma unroll
            for (int mi = 0; mi < 2; ++mi)
                a[mi] = *(const short8*)&As[((wr * 32 + mi * 16 + row) * 8 + rd8) * 8];
            #pragma unroll
            for (int ni = 0; ni < 2; ++ni)
                b[ni] = *(const short8*)&Bs[((wc * 32 + ni * 16 + row) * 8 + rd8) * 8];
            #pragma unroll
            for (int mi = 0; mi < 2; ++mi)
                #pragma unroll
                for (int ni = 0; ni < 2; ++ni)
                    acc[mi][ni] = __builtin_amdgcn_mfma_f32_16x16x32_bf16(a[mi], b[ni], acc[mi][ni], 0, 0, 0);
        }
        __syncthreads();
    }

    int col_l = lane & 15, row_l = (lane >> 4) * 4;
    #pragma unroll
    for (int mi = 0; mi < 2; ++mi) {
        int row0 = bm * 64 + wr * 32 + mi * 16 + row_l;
        #pragma unroll
        for (int ni = 0; ni < 2; ++ni) {
            int col = bn * 64 + wc * 32 + ni * 16 + col_l;
            #pragma unroll
            for (int r = 0; r < 4; ++r)
                C[(size_t)(row0 + r) * N + col] = __float2bfloat16(acc[mi][ni][r]);
        }
    }
}

// ---------------------------------------------------------------- K1: key | Wv-cvt | WoT-transpose | bvo ----
__global__ __launch_bounds__(256) void k_prep1(
    const float* __restrict__ nodes, const float* __restrict__ Wk, const float* __restrict__ bk,
    float* __restrict__ key,
    const float* __restrict__ Wv, const float* __restrict__ Wo,
    bf16* __restrict__ Wv_bf, bf16* __restrict__ WoT_bf,
    const float* __restrict__ bv, const float* __restrict__ bo, float* __restrict__ bvo) {
    __shared__ __align__(16) float lds[64 * 65];
    int u = blockIdx.x, tid = threadIdx.x;
    if (u < 56) {
        int t = u >> 3, dc = u & 7;
        int d_l = tid & 63, q = tid >> 6;
        int d = dc * 64 + d_l;
        float acc = 0.f;
        const float* nr = nodes + t * CI;
        #pragma unroll 4
        for (int c = q * 128; c < q * 128 + 128; ++c)
            acc = fmaf(nr[c], Wk[(size_t)c * CI + d], acc);
        lds[q * 64 + d_l] = acc;
        __syncthreads();
        if (q == 0)
            key[t * CI + d] = lds[d_l] + lds[64 + d_l] + lds[128 + d_l] + lds[192 + d_l] + bk[d];
    } else if (u < 568) {
        int i4 = ((u - 56) * 256 + tid) * 4;
        f32x4 v = *(const f32x4*)&Wv[i4];
        s16x4 o;
        #pragma unroll
        for (int j = 0; j < 4; ++j) { bf16 h = __float2bfloat16(v[j]); o[j] = *(short*)&h; }
        *(s16x4*)&Wv_bf[i4] = o;
    } else if (u < 696) {
        int u3 = u - 568;
        int dt = u3 >> 4, ct = u3 & 15;
        int r0 = tid >> 6, c = tid & 63;
        #pragma unroll
        for (int k = 0; k < 16; ++k) {
            int r = k * 4 + r0;
            lds[r * 65 + c] = Wo[(size_t)(dt * 64 + r) * CIN + ct * 64 + c];
        }
        __syncthreads();
        #pragma unroll
        for (int k = 0; k < 16; ++k) {
            int r = k * 4 + r0;
            WoT_bf[(size_t)(ct * 64 + r) * CI + dt * 64 + c] = __float2bfloat16(lds[c * 65 + r]);
        }
    } else {
        int cp0 = (u - 696) * 32;
        int cp_l = tid & 31, dq = tid >> 5;
        float acc = 0.f;
        #pragma unroll 4
        for (int d = dq * 64; d < dq * 64 + 64; ++d)
            acc = fmaf(bv[d], Wo[(size_t)d * CIN + cp0 + cp_l], acc);
        lds[dq * 32 + cp_l] = acc;
        __syncthreads();
        if (dq == 0) {
            float v = bo[cp0 + cp_l];
            #pragma unroll
            for (int g = 0; g < 8; ++g) v += lds[g * 32 + cp_l];
            bvo[cp0 + cp_l] = v;
        }
    }
}

// ---------------------------------------------------------------- K2: wqk only ----
__global__ __launch_bounds__(256) void k_wqk(
    const float* __restrict__ Wq, const float* __restrict__ bq,
    const float* __restrict__ key, float* __restrict__ Wqk, float* __restrict__ bqk) {
    int c = blockIdx.x * 4 + (threadIdx.x >> 6);
    int lane = threadIdx.x & 63;
    if (c > CIN) return;
    const float* src = (c < CIN) ? (Wq + (size_t)c * CI) : bq;
    float acc[TT] = {};
    #pragma unroll 2
    for (int it = 0; it < CI / 64; ++it) {
        float w = src[it * 64 + lane];
        #pragma unroll
        for (int t = 0; t < TT; ++t) acc[t] = fmaf(w, key[t * CI + it * 64 + lane], acc[t]);
    }
    #pragma unroll
    for (int t = 0; t < TT; ++t) {
        float v = acc[t];
        for (int off = 32; off; off >>= 1) v += __shfl_down(v, off);
        if (lane == 0) { if (c < CIN) Wqk[c * 8 + t] = v; else bqk[t] = v; }
    }
}

// ---------------------------------------------------------------- K3: alpha partials (NCH=32) ----
// 1024 blocks (4/CU): half the per-block strided-load chain, 2x latency hiding.
__global__ __launch_bounds__(256) void k_alpha(const float* __restrict__ x,
                                               const float* __restrict__ Wqk,
                                               float* __restrict__ part) {
    __shared__ float wq_s[CSZ * 8];
    int ch = blockIdx.x, b = blockIdx.y;
    int tid = threadIdx.x;
    for (int i = tid; i < CSZ * 8; i += 256) wq_s[i] = Wqk[ch * CSZ * 8 + i];
    __syncthreads();
    if (tid < HHWW) {
        float acc[TT] = {};
        const float* xb = x + (size_t)(b * CIN + ch * CSZ) * TT * HHWW + TMID * HHWW + tid;
        #pragma unroll 8
        for (int c = 0; c < CSZ; ++c) {
            float v = xb[(size_t)c * TT * HHWW];
            #pragma unroll
            for (int t = 0; t < TT; ++t) acc[t] = fmaf(v, wq_s[c * 8 + t], acc[t]);
        }
        #pragma unroll
        for (int t = 0; t < TT; ++t)
            part[((size_t)(b * NCH + ch) * TT + t) * HHWW + tid] = acc[t];
    }
}

// ---------------------------------------------------------------- K3.5: softmax -> alphaF ----
__global__ __launch_bounds__(256) void k_softmaxF(const float* __restrict__ part,
                                                  const float* __restrict__ bqk,
                                                  float* __restrict__ alphaF) {
    int b = blockIdx.x;
    int tid = threadIdx.x;
    if (tid >= HHWW) return;
    float s[TT];
    #pragma unroll
    for (int t = 0; t < TT; ++t) s[t] = bqk[t];
    for (int ch = 0; ch < NCH; ++ch)
        #pragma unroll
        for (int t = 0; t < TT; ++t)
            s[t] += part[((size_t)(b * NCH + ch) * TT + t) * HHWW + tid];
    float mx = s[0];
    #pragma unroll
    for (int t = 1; t < TT; ++t) mx = fmaxf(mx, s[t]);
    float e[TT], sum = 0.f;
    #pragma unroll
    for (int t = 0; t < TT; ++t) { e[t] = __expf(s[t] - mx); sum += e[t]; }
    float inv = 1.f / sum;
    #pragma unroll
    for (int t = 0; t < TT; ++t) alphaF[(size_t)b * TT * HHWW + t * HHWW + tid] = e[t] * inv;
}

// ---------------------------------------------------------------- K4: smxw | gemm0 (merged) ----
// Blocks 0..255: gemm0 64x64 tiles (hidden under smxw's 31us BW phase; m114 overlap).
// Blocks 256..1279: smxw units. 1280 = 5*256: balanced rounds. LDS 18KB union.
__global__ __launch_bounds__(256) void k_smxwg0(
    const float* __restrict__ x, const float* __restrict__ alphaF, bf16* __restrict__ xw,
    const bf16* __restrict__ WoT_bf, const bf16* __restrict__ Wv_bf, bf16* __restrict__ WvoT) {
    __shared__ __align__(16) char smem[18048];   // max(smxw 18032, gemm0 16384)
    int bid = blockIdx.x, tid = threadIdx.x;
    if (bid < 256) {
        gemm0_small(WoT_bf, Wv_bf, WvoT, bid >> 4, bid & 15, smem);
        return;
    }
    float* al = (float*)smem;                    // 5488 B
    bf16* txp = (bf16*)(smem + 5504);            // 12544 B
    int u = bid - 256;
    int c0 = (u & 31) * 32;
    int b = u >> 5;
    for (int i = tid; i < TT * HHWW; i += 256) al[i] = alphaF[(size_t)b * TT * HHWW + i];
    __syncthreads();
    const f32x4* xp = (const f32x4*)x;
    f32x4 acc[7] = {};
    #pragma unroll
    for (int t = 0; t < TT; ++t) {
        #pragma unroll
        for (int k = 0; k < 7; ++k) {
            int w = k * 256 + tid;
            if (k == 6 && w >= 1568) continue;
            int c_l = w / 49;
            int hw4 = w - c_l * 49;
            f32x4 a4 = *(const f32x4*)&al[t * HHWW + hw4 * 4];
            f32x4 xv = xp[((size_t)(b * CIN + c0 + c_l) * TT + t) * HW4 + hw4];
            acc[k] += a4 * xv;
        }
    }
    #pragma unroll
    for (int k = 0; k < 7; ++k) {
        int w = k * 256 + tid;
        if (k == 6 && w >= 1568) continue;
        int c_l = w / 49;
        int hw4 = w - c_l * 49;
        int v = (hw4 & 7) << 2;
        #pragma unroll
        for (int r = 0; r < 4; ++r)
            txp[(hw4 * 4 + r) * 32 + (c_l ^ v)] = __float2bfloat16(acc[k][r]);
    }
    __syncthreads();
    #pragma unroll
    for (int k = 0; k < 7; ++k) {
        int w = k * 256 + tid;
        if (k == 6 && w >= 1568) continue;
        int m = w >> 3, seg = w & 7;
        int v = ((m >> 2) & 7) << 2;
        s16x4 val = *(const s16x4*)&txp[m * 32 + ((seg * 4) ^ v)];
        *(s16x4*)&xw[(size_t)(b * HHWW + m) * CIN + c0 + seg * 4] = val;
    }
}

// ---------------------------------------------------------------- K5: main GEMM (dbuf, counted vmcnt, swizzled) ----
__global__ __launch_bounds__(256) void k_gemm1(const bf16* __restrict__ A, const bf16* __restrict__ Bt,
                                               float* __restrict__ C, const float* __restrict__ bias) {
    __shared__ __align__(16) bf16 As[2 * 128 * 64];
    __shared__ __align__(16) bf16 Bs[2 * 128 * 64];
    gemm_body<1>(A, Bt, (void*)C, bias, MM, CIN, CIN, blockIdx.x, blockIdx.y, As, Bs);
}

// ---------------------------------------------------------------- launch ----
extern "C" void kernel_launch(void* const* d_in, const int* in_sizes, int n_in,
                              void* d_out, int out_size, void* d_ws, size_t ws_size,
                              hipStream_t stream) {
    const float* x     = (const float*)d_in[0];
    const float* nodes = (const float*)d_in[1];
    const float* Wq    = (const float*)d_in[2];
    const float* bq    = (const float*)d_in[3];
    const float* Wk    = (const float*)d_in[4];
    const float* bk    = (const float*)d_in[5];
    const float* Wv    = (const float*)d_in[6];
    const float* bv    = (const float*)d_in[7];
    const float* Wo    = (const float*)d_in[8];
    const float* bo    = (const float*)d_in[9];

    uint8_t* w = (uint8_t*)d_ws;
    size_t off = 0;
    auto alloc = [&](size_t bytes) -> void* {
        void* p = w + off;
        off = (off + bytes + 255) & ~(size_t)255;
        return p;
    };
    float* key    = (float*)alloc((size_t)TT * CI * 4);
    float* Wqk    = (float*)alloc((size_t)CIN * 8 * 4);
    float* bqk    = (float*)alloc(8 * 4);
    float* bvo    = (float*)alloc((size_t)CIN * 4);
    bf16*  Wv_bf  = (bf16*)alloc((size_t)CIN * CI * 2);
    bf16*  WoT_bf = (bf16*)alloc((size_t)CIN * CI * 2);
    bf16*  WvoT   = (bf16*)alloc((size_t)CIN * CIN * 2);
    float* part   = (float*)alloc((size_t)BB * NCH * TT * HHWW * 4);
    float* alphaF = (float*)alloc((size_t)BB * TT * HHWW * 4);
    bf16*  xw     = (bf16*)alloc((size_t)MM * CIN * 2);
    (void)ws_size;  // ~24 MB

    k_prep1<<<728, 256, 0, stream>>>(nodes, Wk, bk, key, Wv, Wo, Wv_bf, WoT_bf, bv, bo, bvo);
    k_wqk<<<257, 256, 0, stream>>>(Wq, bq, key, Wqk, bqk);
    k_alpha<<<dim3(NCH, BB), 256, 0, stream>>>(x, Wqk, part);
    k_softmaxF<<<BB, 256, 0, stream>>>(part, bqk, alphaF);
    k_smxwg0<<<1280, 256, 0, stream>>>(x, alphaF, xw, WoT_bf, Wv_bf, WvoT);
    k_gemm1<<<dim3(49, 8), 256, 0, stream>>>(xw, WvoT, (float*)d_out, bvo);
}

// Round 26
// 87.865 us; speedup vs baseline: 1.1735x; 1.1735x over previous
//
#include <hip/hip_runtime.h>
#include <hip/hip_bf16.h>
#include <stdint.h>

// Problem constants
#define BB    32
#define CIN   1024
#define TT    7
#define HHWW  196      // 14*14
#define HW4   49       // 196/4
#define CI    512      // C_INTER
#define TMID  3
#define MM    (BB*HHWW)   // 6272 = 49*128
#define NCH   16          // alpha c-chunks
#define CSZ   64          // c per chunk

using bf16 = __hip_bfloat16;
typedef __attribute__((ext_vector_type(8))) short short8;
typedef __attribute__((ext_vector_type(4))) short s16x4;
typedef __attribute__((ext_vector_type(4))) float f32x4;

__device__ __forceinline__ void gload_lds16(const void* g, void* l) {
    __builtin_amdgcn_global_load_lds((const __attribute__((address_space(1))) void*)g,
                                     (__attribute__((address_space(3))) void*)l, 16, 0, 0);
}

// ---------------------------------------------------------------- GEMM body (128x128, dbuf, counted vmcnt, T2 swizzle) ----
// TN: A[m][k], Bt[n][k], bf16, f32 accum. 256 threads, 2x2 waves.
// LDS: 16B granule g holds global (r=g>>3, c8=(g&7)^(r&7)) — XOR spread across 8
// bank-quads; linear gload_lds dest + pre-swizzled global src + swizzled read (rule #21).
// Per K-iter: stage(next) -> s_waitcnt vmcnt(8) -> s_barrier -> ds_read+MFMA -> s_barrier.
template <int EPI>
__device__ __forceinline__ void gemm_body(const bf16* __restrict__ A, const bf16* __restrict__ Bt,
                                          void* __restrict__ Cout, const float* __restrict__ bias,
                                          int M, int N, int K, int bm, int bn,
                                          bf16* As, bf16* Bs) {
    int tid = threadIdx.x;
    int wid = tid >> 6, lane = tid & 63;
    int wr = wid >> 1, wc = wid & 1;
    f32x4 acc[4][4] = {};
    const bf16* Ab = A + (size_t)bm * 128 * K;
    const bf16* Bb = Bt + (size_t)bn * 128 * K;
    int row = lane & 15;
    int sw = row & 7;

    auto stage = [&](int buf, int k0) {
        #pragma unroll
        for (int it = 0; it < 4; ++it) {
            int g = it * 256 + tid;
            int r = g >> 3;
            int src8 = (g & 7) ^ (r & 7);
            gload_lds16(Ab + (size_t)r * K + k0 + src8 * 8, &As[buf * 8192 + g * 8]);
            gload_lds16(Bb + (size_t)r * K + k0 + src8 * 8, &Bs[buf * 8192 + g * 8]);
        }
    };

    stage(0, 0);
    int cur = 0;
    for (int k0 = 0; k0 < K; k0 += 64) {
        if (k0 + 64 < K) {
            stage(cur ^ 1, k0 + 64);
            asm volatile("s_waitcnt vmcnt(8)" ::: "memory");
        } else {
            asm volatile("s_waitcnt vmcnt(0)" ::: "memory");
        }
        __builtin_amdgcn_s_barrier();
        bf16* Ac = &As[cur * 8192];
        bf16* Bc = &Bs[cur * 8192];
        #pragma unroll
        for (int kk = 0; kk < 2; ++kk) {
            int kb8 = kk * 4 + (lane >> 4);
            int rd8 = kb8 ^ sw;
            short8 a[4], b[4];
            #pragma unroll
            for (int mi = 0; mi < 4; ++mi) {
                int arow = wr * 64 + mi * 16 + row;
                a[mi] = *(const short8*)&Ac[(arow * 8 + rd8) * 8];
            }
            #pragma unroll
            for (int ni = 0; ni < 4; ++ni) {
                int brow = wc * 64 + ni * 16 + row;
                b[ni] = *(const short8*)&Bc[(brow * 8 + rd8) * 8];
            }
            #pragma unroll
            for (int mi = 0; mi < 4; ++mi)
                #pragma unroll
                for (int ni = 0; ni < 4; ++ni)
                    acc[mi][ni] = __builtin_amdgcn_mfma_f32_16x16x32_bf16(a[mi], b[ni], acc[mi][ni], 0, 0, 0);
        }
        __builtin_amdgcn_s_barrier();
        cur ^= 1;
    }

    int col_l = lane & 15, row_l = (lane >> 4) * 4;
    if constexpr (EPI == 0) {
        bf16* C = (bf16*)Cout;
        #pragma unroll
        for (int mi = 0; mi < 4; ++mi) {
            int row0 = bm * 128 + wr * 64 + mi * 16 + row_l;
            #pragma unroll
            for (int ni = 0; ni < 4; ++ni) {
                int col = bn * 128 + wc * 64 + ni * 16 + col_l;
                #pragma unroll
                for (int r = 0; r < 4; ++r)
                    C[(size_t)(row0 + r) * N + col] = __float2bfloat16(acc[mi][ni][r]);
            }
        }
    } else {
        float* Cf = (float*)Cout;
        #pragma unroll
        for (int ni = 0; ni < 4; ++ni) {
            int n = bn * 128 + wc * 64 + ni * 16 + col_l;
            float bz = bias[n];
            #pragma unroll
            for (int mi = 0; mi < 4; ++mi) {
                int m0 = bm * 128 + wr * 64 + mi * 16 + row_l;
                int b = m0 / HHWW;
                int hw0 = m0 - b * HHWW;
                f32x4 v = acc[mi][ni];
                v[0] += bz; v[1] += bz; v[2] += bz; v[3] += bz;
                *(f32x4*)&Cf[((size_t)b * CIN + n) * HHWW + hw0] = v;
            }
        }
    }
}

// ---------------------------------------------------------------- gemm0 small body (64x64, single-buf, T2 swizzle) ----
// Hidden under smxw's BW phase — simplicity over peak. 256 thr = 2x2 waves, 32x32 out each.
__device__ __forceinline__ void gemm0_small(const bf16* __restrict__ A, const bf16* __restrict__ Bt,
                                            bf16* __restrict__ C, int bm, int bn, char* smem) {
    bf16* As = (bf16*)smem;            // 8 KB
    bf16* Bs = (bf16*)(smem + 8192);   // 8 KB
    const int K = 512, N = 1024;
    int tid = threadIdx.x;
    int wid = tid >> 6, lane = tid & 63;
    int wr = wid >> 1, wc = wid & 1;
    f32x4 acc[2][2] = {};
    const bf16* Ab = A + (size_t)bm * 64 * K;
    const bf16* Bb = Bt + (size_t)bn * 64 * K;
    int row = lane & 15;
    int sw = row & 7;

    for (int k0 = 0; k0 < K; k0 += 64) {
        #pragma unroll
        for (int it = 0; it < 2; ++it) {
            int g = it * 256 + tid;
            int r = g >> 3;
            int src8 = (g & 7) ^ (r & 7);
            gload_lds16(Ab + (size_t)r * K + k0 + src8 * 8, &As[g * 8]);
            gload_lds16(Bb + (size_t)r * K + k0 + src8 * 8, &Bs[g * 8]);
        }
        __syncthreads();
        #pragma unroll
        for (int kk = 0; kk < 2; ++kk) {
            int kb8 = kk * 4 + (lane >> 4);
            int rd8 = kb8 ^ sw;
            short8 a[2], b[2];
            #pragma unroll
            for (int mi = 0; mi < 2; ++mi)
                a[mi] = *(const short8*)&As[((wr * 32 + mi * 16 + row) * 8 + rd8) * 8];
            #pragma unroll
            for (int ni = 0; ni < 2; ++ni)
                b[ni] = *(const short8*)&Bs[((wc * 32 + ni * 16 + row) * 8 + rd8) * 8];
            #pragma unroll
            for (int mi = 0; mi < 2; ++mi)
                #pragma unroll
                for (int ni = 0; ni < 2; ++ni)
                    acc[mi][ni] = __builtin_amdgcn_mfma_f32_16x16x32_bf16(a[mi], b[ni], acc[mi][ni], 0, 0, 0);
        }
        __syncthreads();
    }

    int col_l = lane & 15, row_l = (lane >> 4) * 4;
    #pragma unroll
    for (int mi = 0; mi < 2; ++mi) {
        int row0 = bm * 64 + wr * 32 + mi * 16 + row_l;
        #pragma unroll
        for (int ni = 0; ni < 2; ++ni) {
            int col = bn * 64 + wc * 32 + ni * 16 + col_l;
            #pragma unroll
            for (int r = 0; r < 4; ++r)
                C[(size_t)(row0 + r) * N + col] = __float2bfloat16(acc[mi][ni][r]);
        }
    }
}

// ---------------------------------------------------------------- K1: key | Wv-cvt | WoT-transpose | bvo ----
__global__ __launch_bounds__(256) void k_prep1(
    const float* __restrict__ nodes, const float* __restrict__ Wk, const float* __restrict__ bk,
    float* __restrict__ key,
    const float* __restrict__ Wv, const float* __restrict__ Wo,
    bf16* __restrict__ Wv_bf, bf16* __restrict__ WoT_bf,
    const float* __restrict__ bv, const float* __restrict__ bo, float* __restrict__ bvo) {
    __shared__ __align__(16) float lds[64 * 65];
    int u = blockIdx.x, tid = threadIdx.x;
    if (u < 56) {
        int t = u >> 3, dc = u & 7;
        int d_l = tid & 63, q = tid >> 6;
        int d = dc * 64 + d_l;
        float acc = 0.f;
        const float* nr = nodes + t * CI;
        #pragma unroll 4
        for (int c = q * 128; c < q * 128 + 128; ++c)
            acc = fmaf(nr[c], Wk[(size_t)c * CI + d], acc);
        lds[q * 64 + d_l] = acc;
        __syncthreads();
        if (q == 0)
            key[t * CI + d] = lds[d_l] + lds[64 + d_l] + lds[128 + d_l] + lds[192 + d_l] + bk[d];
    } else if (u < 568) {
        int i4 = ((u - 56) * 256 + tid) * 4;
        f32x4 v = *(const f32x4*)&Wv[i4];
        s16x4 o;
        #pragma unroll
        for (int j = 0; j < 4; ++j) { bf16 h = __float2bfloat16(v[j]); o[j] = *(short*)&h; }
        *(s16x4*)&Wv_bf[i4] = o;
    } else if (u < 696) {
        int u3 = u - 568;
        int dt = u3 >> 4, ct = u3 & 15;
        int r0 = tid >> 6, c = tid & 63;
        #pragma unroll
        for (int k = 0; k < 16; ++k) {
            int r = k * 4 + r0;
            lds[r * 65 + c] = Wo[(size_t)(dt * 64 + r) * CIN + ct * 64 + c];
        }
        __syncthreads();
        #pragma unroll
        for (int k = 0; k < 16; ++k) {
            int r = k * 4 + r0;
            WoT_bf[(size_t)(ct * 64 + r) * CI + dt * 64 + c] = __float2bfloat16(lds[c * 65 + r]);
        }
    } else {
        int cp0 = (u - 696) * 32;
        int cp_l = tid & 31, dq = tid >> 5;
        float acc = 0.f;
        #pragma unroll 4
        for (int d = dq * 64; d < dq * 64 + 64; ++d)
            acc = fmaf(bv[d], Wo[(size_t)d * CIN + cp0 + cp_l], acc);
        lds[dq * 32 + cp_l] = acc;
        __syncthreads();
        if (dq == 0) {
            float v = bo[cp0 + cp_l];
            #pragma unroll
            for (int g = 0; g < 8; ++g) v += lds[g * 32 + cp_l];
            bvo[cp0 + cp_l] = v;
        }
    }
}

// ---------------------------------------------------------------- K2: wqk only ----
__global__ __launch_bounds__(256) void k_wqk(
    const float* __restrict__ Wq, const float* __restrict__ bq,
    const float* __restrict__ key, float* __restrict__ Wqk, float* __restrict__ bqk) {
    int c = blockIdx.x * 4 + (threadIdx.x >> 6);
    int lane = threadIdx.x & 63;
    if (c > CIN) return;
    const float* src = (c < CIN) ? (Wq + (size_t)c * CI) : bq;
    float acc[TT] = {};
    #pragma unroll 2
    for (int it = 0; it < CI / 64; ++it) {
        float w = src[it * 64 + lane];
        #pragma unroll
        for (int t = 0; t < TT; ++t) acc[t] = fmaf(w, key[t * CI + it * 64 + lane], acc[t]);
    }
    #pragma unroll
    for (int t = 0; t < TT; ++t) {
        float v = acc[t];
        for (int off = 32; off; off >>= 1) v += __shfl_down(v, off);
        if (lane == 0) { if (c < CIN) Wqk[c * 8 + t] = v; else bqk[t] = v; }
    }
}

// ---------------------------------------------------------------- K3: alpha partials ----
__global__ __launch_bounds__(256) void k_alpha(const float* __restrict__ x,
                                               const float* __restrict__ Wqk,
                                               float* __restrict__ part) {
    __shared__ float wq_s[CSZ * 8];
    int ch = blockIdx.x, b = blockIdx.y;
    int tid = threadIdx.x;
    for (int i = tid; i < CSZ * 8; i += 256) wq_s[i] = Wqk[ch * CSZ * 8 + i];
    __syncthreads();
    if (tid < HHWW) {
        float acc[TT] = {};
        const float* xb = x + (size_t)(b * CIN + ch * CSZ) * TT * HHWW + TMID * HHWW + tid;
        #pragma unroll 8
        for (int c = 0; c < CSZ; ++c) {
            float v = xb[(size_t)c * TT * HHWW];
            #pragma unroll
            for (int t = 0; t < TT; ++t) acc[t] = fmaf(v, wq_s[c * 8 + t], acc[t]);
        }
        #pragma unroll
        for (int t = 0; t < TT; ++t)
            part[((size_t)(b * NCH + ch) * TT + t) * HHWW + tid] = acc[t];
    }
}

// ---------------------------------------------------------------- K3.5: softmax -> alphaF ----
__global__ __launch_bounds__(256) void k_softmaxF(const float* __restrict__ part,
                                                  const float* __restrict__ bqk,
                                                  float* __restrict__ alphaF) {
    int b = blockIdx.x;
    int tid = threadIdx.x;
    if (tid >= HHWW) return;
    float s[TT];
    #pragma unroll
    for (int t = 0; t < TT; ++t) s[t] = bqk[t];
    #pragma unroll
    for (int ch = 0; ch < NCH; ++ch)
        #pragma unroll
        for (int t = 0; t < TT; ++t)
            s[t] += part[((size_t)(b * NCH + ch) * TT + t) * HHWW + tid];
    float mx = s[0];
    #pragma unroll
    for (int t = 1; t < TT; ++t) mx = fmaxf(mx, s[t]);
    float e[TT], sum = 0.f;
    #pragma unroll
    for (int t = 0; t < TT; ++t) { e[t] = __expf(s[t] - mx); sum += e[t]; }
    float inv = 1.f / sum;
    #pragma unroll
    for (int t = 0; t < TT; ++t) alphaF[(size_t)b * TT * HHWW + t * HHWW + tid] = e[t] * inv;
}

// ---------------------------------------------------------------- K4: smxw | gemm0 (merged) ----
// Blocks 0..255: gemm0 64x64 tiles (MFMA-bound, consumed only by gemm1 later) — dispatched
// first, hidden under smxw's 31us BW phase (MFMA pipe idle there; m114 overlap).
// Blocks 256..1279: smxw units. 1280 = 5*256: balanced rounds. LDS 18KB union.
__global__ __launch_bounds__(256) void k_smxwg0(
    const float* __restrict__ x, const float* __restrict__ alphaF, bf16* __restrict__ xw,
    const bf16* __restrict__ WoT_bf, const bf16* __restrict__ Wv_bf, bf16* __restrict__ WvoT) {
    __shared__ __align__(16) char smem[18048];   // max(smxw 18032, gemm0 16384)
    int bid = blockIdx.x, tid = threadIdx.x;
    if (bid < 256) {
        gemm0_small(WoT_bf, Wv_bf, WvoT, bid >> 4, bid & 15, smem);
        return;
    }
    float* al = (float*)smem;                    // 5488 B
    bf16* txp = (bf16*)(smem + 5504);            // 12544 B
    int u = bid - 256;
    int c0 = (u & 31) * 32;
    int b = u >> 5;
    for (int i = tid; i < TT * HHWW; i += 256) al[i] = alphaF[(size_t)b * TT * HHWW + i];
    __syncthreads();
    const f32x4* xp = (const f32x4*)x;
    f32x4 acc[7] = {};
    #pragma unroll
    for (int t = 0; t < TT; ++t) {
        #pragma unroll
        for (int k = 0; k < 7; ++k) {
            int w = k * 256 + tid;
            if (k == 6 && w >= 1568) continue;
            int c_l = w / 49;
            int hw4 = w - c_l * 49;
            f32x4 a4 = *(const f32x4*)&al[t * HHWW + hw4 * 4];
            f32x4 xv = xp[((size_t)(b * CIN + c0 + c_l) * TT + t) * HW4 + hw4];
            acc[k] += a4 * xv;
        }
    }
    #pragma unroll
    for (int k = 0; k < 7; ++k) {
        int w = k * 256 + tid;
        if (k == 6 && w >= 1568) continue;
        int c_l = w / 49;
        int hw4 = w - c_l * 49;
        int v = (hw4 & 7) << 2;
        #pragma unroll
        for (int r = 0; r < 4; ++r)
            txp[(hw4 * 4 + r) * 32 + (c_l ^ v)] = __float2bfloat16(acc[k][r]);
    }
    __syncthreads();
    #pragma unroll
    for (int k = 0; k < 7; ++k) {
        int w = k * 256 + tid;
        if (k == 6 && w >= 1568) continue;
        int m = w >> 3, seg = w & 7;
        int v = ((m >> 2) & 7) << 2;
        s16x4 val = *(const s16x4*)&txp[m * 32 + ((seg * 4) ^ v)];
        *(s16x4*)&xw[(size_t)(b * HHWW + m) * CIN + c0 + seg * 4] = val;
    }
}

// ---------------------------------------------------------------- K5: main GEMM (dbuf, counted vmcnt, swizzled) ----
__global__ __launch_bounds__(256) void k_gemm1(const bf16* __restrict__ A, const bf16* __restrict__ Bt,
                                               float* __restrict__ C, const float* __restrict__ bias) {
    __shared__ __align__(16) bf16 As[2 * 128 * 64];
    __shared__ __align__(16) bf16 Bs[2 * 128 * 64];
    gemm_body<1>(A, Bt, (void*)C, bias, MM, CIN, CIN, blockIdx.x, blockIdx.y, As, Bs);
}

// ---------------------------------------------------------------- launch ----
extern "C" void kernel_launch(void* const* d_in, const int* in_sizes, int n_in,
                              void* d_out, int out_size, void* d_ws, size_t ws_size,
                              hipStream_t stream) {
    const float* x     = (const float*)d_in[0];
    const float* nodes = (const float*)d_in[1];
    const float* Wq    = (const float*)d_in[2];
    const float* bq    = (const float*)d_in[3];
    const float* Wk    = (const float*)d_in[4];
    const float* bk    = (const float*)d_in[5];
    const float* Wv    = (const float*)d_in[6];
    const float* bv    = (const float*)d_in[7];
    const float* Wo    = (const float*)d_in[8];
    const float* bo    = (const float*)d_in[9];

    uint8_t* w = (uint8_t*)d_ws;
    size_t off = 0;
    auto alloc = [&](size_t bytes) -> void* {
        void* p = w + off;
        off = (off + bytes + 255) & ~(size_t)255;
        return p;
    };
    float* key    = (float*)alloc((size_t)TT * CI * 4);
    float* Wqk    = (float*)alloc((size_t)CIN * 8 * 4);
    float* bqk    = (float*)alloc(8 * 4);
    float* bvo    = (float*)alloc((size_t)CIN * 4);
    bf16*  Wv_bf  = (bf16*)alloc((size_t)CIN * CI * 2);
    bf16*  WoT_bf = (bf16*)alloc((size_t)CIN * CI * 2);
    bf16*  WvoT   = (bf16*)alloc((size_t)CIN * CIN * 2);
    float* part   = (float*)alloc((size_t)BB * NCH * TT * HHWW * 4);
    float* alphaF = (float*)alloc((size_t)BB * TT * HHWW * 4);
    bf16*  xw     = (bf16*)alloc((size_t)MM * CIN * 2);
    (void)ws_size;  // ~21 MB

    k_prep1<<<728, 256, 0, stream>>>(nodes, Wk, bk, key, Wv, Wo, Wv_bf, WoT_bf, bv, bo, bvo);
    k_wqk<<<257, 256, 0, stream>>>(Wq, bq, key, Wqk, bqk);
    k_alpha<<<dim3(NCH, BB), 256, 0, stream>>>(x, Wqk, part);
    k_softmaxF<<<BB, 256, 0, stream>>>(part, bqk, alphaF);
    k_smxwg0<<<1280, 256, 0, stream>>>(x, alphaF, xw, WoT_bf, Wv_bf, WvoT);
    k_gemm1<<<dim3(49, 8), 256, 0, stream>>>(xw, WvoT, (float*)d_out, bvo);
}